// Round 11
// baseline (74.985 us; speedup 1.0000x reference)
//
#include <hip/hip_runtime.h>

// Simple_TensorProduct (e3nn uvw TP, MUL=256, l<=1, v=1) as two fused bf16 GEMMs.
//   out0[z,w]      = sum_k T0[z,k]    * B0[k,w]   (K=512)
//   out1[(z,c),w]  = sum_k T1[(z,c),k]* B1[k,w]   (K=768, M=3N)
// T = x1 with x2 folded in (built per z-tile, bf16, LDS, A-fragment order).
// B = weights, prescaled by path alphas, bf16, B-fragment order in d_ws.
//
// R11: L2-traffic reduction + R10's compiler-proof pipeline.
//  - z-tile 32 (halves B re-read traffic 800->400 MB), u-chunk 64, 4 chunks.
//  - single 45 KB LDS buffer, R3's exact fragment layout/build (passed).
//  - w-split: block covers 128 of 256 cols (grid 1250); 4 waves, ct=2/wave,
//    acc = 16 f32x4. 88 MFMA per wave per phase.
//  - per-chunk asm B-burst (20 int4) covered by build; counted vmcnt(20/8/0);
//    raw lgkmcnt-only barriers; setprio around MFMA cluster.

typedef short bf16x8 __attribute__((ext_vector_type(8)));
typedef float f32x4 __attribute__((ext_vector_type(4)));
typedef int   ni4   __attribute__((ext_vector_type(4)));

static __device__ __forceinline__ unsigned short f2bf(float f) {
  unsigned int u = __builtin_bit_cast(unsigned int, f);
  u += 0x7FFFu + ((u >> 16) & 1u);   // RNE
  return (unsigned short)(u >> 16);
}

static __device__ __forceinline__ bf16x8 asbf(int4 v) {
  return __builtin_bit_cast(bf16x8, v);
}
static __device__ __forceinline__ bf16x8 asbfn(ni4 v) {
  return __builtin_bit_cast(bf16x8, v);
}

static __device__ __forceinline__ void gload4(ni4& dst, const void* p) {
  asm volatile("global_load_dwordx4 %0, %1, off" : "=v"(dst) : "v"(p));
}

#define WAITV(n) do { \
    asm volatile("s_waitcnt vmcnt(" #n ")"); \
    __builtin_amdgcn_sched_barrier(0); \
  } while (0)

static __device__ __forceinline__ void phase_barrier() {
  __builtin_amdgcn_sched_barrier(0);
  asm volatile("s_waitcnt lgkmcnt(0)");
  __builtin_amdgcn_sched_barrier(0);
  __builtin_amdgcn_s_barrier();
  __builtin_amdgcn_sched_barrier(0);
}

// ---------------------------------------------------------------------------
// Weight prep (u-chunk = 64, c in 0..3; verbatim R10, passed):
// B1: fid = ((c*6+kt)*16+ct)*64+lane; elem e: kc=kt*32+(lane>>4)*8+e (0..191),
//     seg=kc>>6, u=c*64+(kc&63), w=ct*16+(lane&15)
// B0: fid = 24576 + ((c*4+kt)*16+ct)*64+lane; kc 0..127, seg=kc>>6
// ---------------------------------------------------------------------------
__global__ __launch_bounds__(256) void prep_weights(
    const float* __restrict__ wgt, unsigned short* __restrict__ Bw)
{
  int fid = blockIdx.x * 256 + threadIdx.x;
  union { unsigned short h[8]; int4 v; } pk;
  if (fid < 24576) {
    int lane = fid & 63;
    int ct = (fid >> 6) & 15;
    int q = fid >> 10;            // 0..23 = c*6 + kt
    int kt = q % 6, c = q / 6;
    int w = ct * 16 + (lane & 15);
    int kh = (lane >> 4) * 8;
#pragma unroll
    for (int e = 0; e < 8; ++e) {
      int kc = kt * 32 + kh + e;       // 0..191
      int seg = kc >> 6;
      int u = c * 64 + (kc & 63);
      float s  = (seg == 2) ? 0.025515518153991442f : 0.03608439182435161f;
      int off  = (seg == 0) ? 65536 : (seg == 1 ? 131072 : 262144);
      pk.h[e] = f2bf(wgt[off + u * 256 + w] * s);
    }
    ((int4*)Bw)[fid] = pk.v;
  } else if (fid < 40960) {
    int f2 = fid - 24576;
    int lane = f2 & 63;
    int ct = (f2 >> 6) & 15;
    int q = f2 >> 10;             // 0..15 = c*4 + kt
    int kt = q & 3, c = q >> 2;
    int w = ct * 16 + (lane & 15);
    int kh = (lane >> 4) * 8;
#pragma unroll
    for (int e = 0; e < 8; ++e) {
      int kc = kt * 32 + kh + e;       // 0..127
      int seg = kc >> 6;
      int u = c * 64 + (kc & 63);
      float s  = (seg == 0) ? 0.04419417382415922f : 0.025515518153991442f;
      int off  = (seg == 0) ? 0 : 196608;
      pk.h[e] = f2bf(wgt[off + u * 256 + w] * s);
    }
    ((int4*)Bw)[fid] = pk.v;
  }
}

// LDS map (int4 slots), z=32 (R3's exact layout, passed):
//   T1: (row>>4)*384 + kt*64 + perm   (row 0..95, kt 0..5)
//   T0: 2304 + (zl>>4)*256 + kt*64 + perm  (zl 0..31, kt 0..3)
#define T0BASE 2304

struct X1Raw { ni4 a[8]; };   // s1[8] (2 regs) + v1[8u x 3k] (6 regs), raw bits

static __device__ __forceinline__ void load_x1_asm(
    X1Raw& r, const float* __restrict__ x1, int zrow, int ub, int rr)
{
  const float* base = x1 + (size_t)zrow * 1024;
  const float* ps = base + ub + rr * 8;
  gload4(r.a[0], ps);
  gload4(r.a[1], ps + 4);
  const float* pv = base + 256 + 3 * ub + rr * 24;
#pragma unroll
  for (int i = 0; i < 6; ++i) gload4(r.a[2 + i], pv + 4 * i);
}

// thread (zl 0..31, rr 0..7) owns u-run [rr*8, rr*8+8) of the 64-u chunk.
// kc = sg*64 + rr*8 + e -> kt = sg*2 + (rr>>2); lh = rr&3.  (R3 verbatim)
static __device__ __forceinline__ void build_frags(
    const X1Raw& r, int zl, int rr, float s2, const float* v2, int4* ldsT)
{
  union { float4 q[2]; float f[8]; } s1u;
  s1u.q[0] = __builtin_bit_cast(float4, r.a[0]);
  s1u.q[1] = __builtin_bit_cast(float4, r.a[1]);
  union { float4 q[6]; float f[24]; } v1u;
#pragma unroll
  for (int i = 0; i < 6; ++i) v1u.q[i] = __builtin_bit_cast(float4, r.a[2 + i]);
  const int lh = rr & 3;
  const int kq = rr >> 2;

  // ---- T1: seg 0..2 x comp k 0..2 ; row = 3*zl + k (0..95)
#pragma unroll
  for (int sg = 0; sg < 3; ++sg) {
#pragma unroll
    for (int k = 0; k < 3; ++k) {
      int row = 3 * zl + k;
      int kt  = sg * 2 + kq;
      int fl  = (((lh << 4) | (row & 15)) ^ (kt & 7)) ^ lh;
      int addr = (row >> 4) * 384 + kt * 64 + fl;
      float t[8];
      if (sg == 0) {                     // s1 * v2[k]      (-> W2)
#pragma unroll
        for (int e = 0; e < 8; ++e) t[e] = s1u.f[e] * v2[k];
      } else if (sg == 1) {              // v1[.,k] * s2    (-> W3)
#pragma unroll
        for (int e = 0; e < 8; ++e) t[e] = v1u.f[3 * e + k] * s2;
      } else {                           // (v1 x v2)[k]    (-> W5)
        int k1 = k + 1; if (k1 > 2) k1 -= 3;
        int k2 = k + 2; if (k2 > 2) k2 -= 3;
#pragma unroll
        for (int e = 0; e < 8; ++e)
          t[e] = v1u.f[3 * e + k1] * v2[k2] - v1u.f[3 * e + k2] * v2[k1];
      }
      union { unsigned short h[8]; int4 v; } pk;
#pragma unroll
      for (int e = 0; e < 8; ++e) pk.h[e] = f2bf(t[e]);
      ldsT[addr] = pk.v;
    }
  }
  // ---- T0: seg 0..1 ; row = zl (0..31)
#pragma unroll
  for (int sg = 0; sg < 2; ++sg) {
    int kt = sg * 2 + kq;
    int fl = (((lh << 4) | (zl & 15)) ^ (kt & 7)) ^ lh;
    int addr = T0BASE + (zl >> 4) * 256 + kt * 64 + fl;
    float t[8];
    if (sg == 0) {                       // s1 * s2         (-> W1)
#pragma unroll
      for (int e = 0; e < 8; ++e) t[e] = s1u.f[e] * s2;
    } else {                             // v1 . v2         (-> W4)
#pragma unroll
      for (int e = 0; e < 8; ++e) {
        const float* p = v1u.f + 3 * e;
        t[e] = p[0] * v2[0] + p[1] * v2[1] + p[2] * v2[2];
      }
    }
    union { unsigned short h[8]; int4 v; } pk;
#pragma unroll
    for (int e = 0; e < 8; ++e) pk.h[e] = f2bf(t[e]);
    ldsT[addr] = pk.v;
  }
}

// Burst-load this wave's ENTIRE per-chunk B slice (asm, stays in regs):
// vb[0..11] = out1 kt 0..5 x {ct0, ct0+1}; vb[12..19] = out0 kt 0..3.
static __device__ __forceinline__ void burstB(
    ni4 (&vb)[20], const int4* __restrict__ B1v,
    const int4* __restrict__ B0v, int c, int ct0, int lane)
{
#pragma unroll
  for (int s = 0; s < 6; ++s) {
    const int4* p = B1v + ((size_t)((c * 6 + s) * 16 + ct0)) * 64 + lane;
    gload4(vb[s * 2],     p);
    gload4(vb[s * 2 + 1], p + 64);
  }
#pragma unroll
  for (int s = 0; s < 4; ++s) {
    const int4* p = B0v + ((size_t)((c * 4 + s) * 16 + ct0)) * 64 + lane;
    gload4(vb[12 + s * 2],     p);
    gload4(vb[12 + s * 2 + 1], p + 64);
  }
}

// Pure LDS+MFMA gemm for one u-chunk (z=32: 6 row-tiles out1, 2 out0).
static __device__ __forceinline__ void gemm_steps(
    const int4* __restrict__ buf, const ni4 (&vb)[20], int lane,
    f32x4 acc1[6][2], f32x4 acc0[2][2])
{
  __builtin_amdgcn_s_setprio(1);
#pragma unroll
  for (int kt = 0; kt < 6; ++kt) {
    int fl = (lane ^ (kt & 7)) ^ (lane >> 4);
    int4 a[6];
#pragma unroll
    for (int rt = 0; rt < 6; ++rt) a[rt] = buf[rt * 384 + kt * 64 + fl];
#pragma unroll
    for (int rt = 0; rt < 6; ++rt) {
      bf16x8 av = asbf(a[rt]);
#pragma unroll
      for (int j = 0; j < 2; ++j)
        acc1[rt][j] = __builtin_amdgcn_mfma_f32_16x16x32_bf16(
            av, asbfn(vb[kt * 2 + j]), acc1[rt][j], 0, 0, 0);
    }
  }
#pragma unroll
  for (int kt = 0; kt < 4; ++kt) {
    int fl = (lane ^ (kt & 7)) ^ (lane >> 4);
    int4 a0 = buf[T0BASE + kt * 64 + fl];
    int4 a1 = buf[T0BASE + 256 + kt * 64 + fl];
    int4 a[2] = {a0, a1};
#pragma unroll
    for (int rt = 0; rt < 2; ++rt) {
      bf16x8 av = asbf(a[rt]);
#pragma unroll
      for (int j = 0; j < 2; ++j)
        acc0[rt][j] = __builtin_amdgcn_mfma_f32_16x16x32_bf16(
            av, asbfn(vb[12 + kt * 2 + j]), acc0[rt][j], 0, 0, 0);
    }
  }
  __builtin_amdgcn_s_setprio(0);
}

// ---------------------------------------------------------------------------
// Main: 256 threads (4 waves, ct=2 each -> 128 cols), w-split (grid 1250).
// 32 z-rows, 4 u-chunks of 64, single 45 KB LDS buffer.
// Phase c: { burst B(c) | vmcnt(20): x1(c) ready | build(c) | issue x1(c+1) |
//            barrier | vmcnt(8): B ready | gemm(c) | barrier }.
// ---------------------------------------------------------------------------
__global__ __launch_bounds__(256, 2) void tp_main(
    const float* __restrict__ x1, const float* __restrict__ x2,
    const int4* __restrict__ B1v, const int4* __restrict__ B0v,
    float* __restrict__ out)
{
  __shared__ int4 ldsT[2816];           // 45056 bytes
  const int tid  = threadIdx.x;
  const int lane = tid & 63;
  const int wid  = tid >> 6;            // wave 0..3
  const int wh   = blockIdx.x & 1;      // w-half
  const int ct0  = wh * 8 + wid * 2;    // this wave's two 16-col tiles (global)
  const int z0   = (blockIdx.x >> 1) * 32;
  const int zl   = tid >> 3;            // T-build row (0..31)
  const int rr   = tid & 7;             // T-build u-run (0..7)

  f32x4 acc1[6][2];
  f32x4 acc0[2][2];
#pragma unroll
  for (int i = 0; i < 6; ++i)
#pragma unroll
    for (int j = 0; j < 2; ++j) acc1[i][j] = (f32x4){0.f, 0.f, 0.f, 0.f};
#pragma unroll
  for (int i = 0; i < 2; ++i)
#pragma unroll
    for (int j = 0; j < 2; ++j) acc0[i][j] = (f32x4){0.f, 0.f, 0.f, 0.f};

  // x2 via asm + full drain BEFORE any pipelined loads, so the compiler
  // never needs its own vmcnt wait mid-pipeline.
  ni4 x2raw;
  gload4(x2raw, x2 + (size_t)(z0 + zl) * 4);
  WAITV(0);
  float4 x2v = __builtin_bit_cast(float4, x2raw);
  const float s2 = x2v.x;
  float v2[3] = {x2v.y, x2v.z, x2v.w};

  X1Raw rX;
  ni4 vb[20];

  // prologue: x1(0) in flight (8 outstanding)
  load_x1_asm(rX, x1, z0 + zl, 0, rr);

  // ---- phase 0
  burstB(vb, B1v, B0v, 0, ct0, lane);    // out: 8 + 20 = 28
  WAITV(20);                             // x1(0) done
  build_frags(rX, zl, rr, s2, v2, ldsT);
  load_x1_asm(rX, x1, z0 + zl, 64, rr);  // x1(1): out <= 28
  phase_barrier();
  WAITV(8);                              // B(0) done, x1(1) in flight
  gemm_steps(ldsT, vb, lane, acc1, acc0);
  phase_barrier();

  // ---- phase 1
  burstB(vb, B1v, B0v, 1, ct0, lane);
  WAITV(20);                             // x1(1) done
  build_frags(rX, zl, rr, s2, v2, ldsT);
  load_x1_asm(rX, x1, z0 + zl, 128, rr); // x1(2)
  phase_barrier();
  WAITV(8);                              // B(1) done
  gemm_steps(ldsT, vb, lane, acc1, acc0);
  phase_barrier();

  // ---- phase 2
  burstB(vb, B1v, B0v, 2, ct0, lane);
  WAITV(20);                             // x1(2) done
  build_frags(rX, zl, rr, s2, v2, ldsT);
  load_x1_asm(rX, x1, z0 + zl, 192, rr); // x1(3)
  phase_barrier();
  WAITV(8);                              // B(2) done
  gemm_steps(ldsT, vb, lane, acc1, acc0);
  phase_barrier();

  // ---- phase 3
  burstB(vb, B1v, B0v, 3, ct0, lane);
  WAITV(20);                             // x1(3) done
  build_frags(rX, zl, rr, s2, v2, ldsT);
  phase_barrier();
  WAITV(0);                              // B(3) done
  gemm_steps(ldsT, vb, lane, acc1, acc0);

  // ---- epilogue: accumulators are the final outputs (R3 pattern)
  const int col = lane & 15;
  const int rb  = (lane >> 4) * 4;       // C/D: col=lane&15, row=(lane>>4)*4+reg
#pragma unroll
  for (int rt = 0; rt < 2; ++rt) {
#pragma unroll
    for (int j = 0; j < 2; ++j) {
      int w = (ct0 + j) * 16 + col;
#pragma unroll
      for (int rg = 0; rg < 4; ++rg) {
        int row = rt * 16 + rb + rg;     // zl 0..31
        out[(size_t)(z0 + row) * 1024 + w] = acc0[rt][j][rg];
      }
    }
  }
#pragma unroll
  for (int rt = 0; rt < 6; ++rt) {
#pragma unroll
    for (int j = 0; j < 2; ++j) {
      int w = (ct0 + j) * 16 + col;
#pragma unroll
      for (int rg = 0; rg < 4; ++rg) {
        int row = rt * 16 + rb + rg;     // 0..95 ; row = 3*zl + k
        int zz = row / 3;
        int k  = row - zz * 3;
        out[(size_t)(z0 + zz) * 1024 + 256 + w * 3 + k] = acc1[rt][j][rg];
      }
    }
  }
}

// ---------------------------------------------------------------------------
extern "C" void kernel_launch(void* const* d_in, const int* in_sizes, int n_in,
                              void* d_out, int out_size, void* d_ws, size_t ws_size,
                              hipStream_t stream) {
  const float* x1  = (const float*)d_in[0];   // (n, 1024) f32
  const float* x2  = (const float*)d_in[1];   // (n, 4)    f32
  const float* wgt = (const float*)d_in[2];   // (327680,) f32
  float* out = (float*)d_out;                 // (n, 1024) f32

  // ws: B1 fragments [0, 393216) + B0 fragments [393216, 655360)  (bf16)
  unsigned short* Bw = (unsigned short*)d_ws;
  const int4* B1v = (const int4*)Bw;
  const int4* B0v = B1v + 24576;

  int n = in_sizes[0] / 1024;                 // 20000 (divisible by 32)

  prep_weights<<<160, 256, 0, stream>>>(wgt, Bw);
  tp_main<<<(n / 32) * 2, 256, 0, stream>>>(x1, x2, B1v, B0v, out);
}